// Round 1
// baseline (2252.153 us; speedup 1.0000x reference)
//
#include <hip/hip_runtime.h>

#define D 128
#define BR 128          // rows per block in fused kernel
#define WS_STRIDE 132   // padded W row stride (floats)
#define LDS_FLOATS (D * BR + D * WS_STRIDE)
#define LDS_BYTES (LDS_FLOATS * 4)

__global__ void count_kernel(const int* __restrict__ dst, int* __restrict__ cnt, int E) {
    int e = blockIdx.x * 256 + threadIdx.x;
    if (e < E) atomicAdd(&cnt[dst[e]], 1);
}

__global__ void inv_kernel(const int* __restrict__ cnt, float* __restrict__ inv, int n) {
    int i = blockIdx.x * 256 + threadIdx.x;
    if (i < n) inv[i] = 1.0f / (float)max(cnt[i], 1);
}

// one thread per (edge, 4-float chunk): gather x[src] row chunk, atomic-add into summed[dst]
__global__ void scatter_kernel(const float* __restrict__ xin, const int* __restrict__ src,
                               const int* __restrict__ dst, float* summed, int E) {
    unsigned gid = blockIdx.x * 256u + threadIdx.x;
    int e = (int)(gid >> 5);
    if (e >= E) return;
    int c = (int)(gid & 31u) << 2;
    int s = src[e], d = dst[e];
    float4 v = *(const float4*)(xin + (size_t)s * D + c);
    float* o = summed + (size_t)d * D + c;
    __hip_atomic_fetch_add(o + 0, v.x, __ATOMIC_RELAXED, __HIP_MEMORY_SCOPE_AGENT);
    __hip_atomic_fetch_add(o + 1, v.y, __ATOMIC_RELAXED, __HIP_MEMORY_SCOPE_AGENT);
    __hip_atomic_fetch_add(o + 2, v.z, __ATOMIC_RELAXED, __HIP_MEMORY_SCOPE_AGENT);
    __hip_atomic_fetch_add(o + 3, v.w, __ATOMIC_RELAXED, __HIP_MEMORY_SCOPE_AGENT);
}

// fused: out = (summed*inv) @ Wl^T + bl + xin @ Wr^T ; LayerNorm(gamma,beta); ReLU
// block = 256 threads (tx 0..15 over j-groups, ty 0..15 over row-groups), 128 rows/block.
// Two passes (Wl with agg, Wr with x) accumulate into the same registers; LDS holds one
// W [128][132] (padded) + one A tile stored k-major [128 k][128 rows].
__global__ __launch_bounds__(256, 1)
void fused_kernel(const float* __restrict__ summed, const float* __restrict__ inv,
                  const float* xin,
                  const float* __restrict__ Wl, const float* __restrict__ bl,
                  const float* __restrict__ Wr,
                  const float* __restrict__ gamma, const float* __restrict__ beta,
                  float* y, int n) {
    extern __shared__ float lds[];
    float* As = lds;            // [128][BR] k-major
    float* Ws = lds + D * BR;   // [128][WS_STRIDE]
    const int tid = threadIdx.x;
    const int tx = tid & 15, ty = tid >> 4;
    const int row0 = blockIdx.x * BR;

    float acc[8][8];
#pragma unroll
    for (int a = 0; a < 8; ++a)
#pragma unroll
        for (int b = 0; b < 8; ++b) acc[a][b] = 0.f;

    const int r = tid >> 1;            // staging row 0..127
    const int h = (tid & 1) << 6;      // staging k-half 0/64
    const int srow = row0 + r;

    for (int pass = 0; pass < 2; ++pass) {
        const float* Wg = pass ? Wr : Wl;
        const float* Ag = pass ? xin : summed;
        const float scale = pass ? 1.0f : ((srow < n) ? inv[srow] : 0.f);
        if (pass) __syncthreads();     // protect LDS before overwrite
        // ---- stage W (flat coalesced read, padded b128 write) ----
        for (int i = tid; i < (D * D) / 4; i += 256) {
            int f = i << 2;
            int j = f >> 7, k = f & (D - 1);
            float4 wv = *(const float4*)(Wg + f);
            *(float4*)(Ws + j * WS_STRIDE + k) = wv;
        }
        // ---- stage A tile k-major, scaled by inv on pass 0 ----
#pragma unroll
        for (int i = 0; i < 16; ++i) {
            float4 v = {0.f, 0.f, 0.f, 0.f};
            if (srow < n) v = *(const float4*)(Ag + (size_t)srow * D + h + (i << 2));
            int k = h + (i << 2);
            As[(k + 0) * BR + r] = v.x * scale;
            As[(k + 1) * BR + r] = v.y * scale;
            As[(k + 2) * BR + r] = v.z * scale;
            As[(k + 3) * BR + r] = v.w * scale;
        }
        __syncthreads();
        // ---- compute: 32 chunks of 4 k ----
        const int ty8 = ty << 3;
        for (int c = 0; c < 32; ++c) {
            float4 w[8];
#pragma unroll
            for (int jj = 0; jj < 8; ++jj)
                w[jj] = *(const float4*)(Ws + (tx + (jj << 4)) * WS_STRIDE + (c << 2));
#pragma unroll
            for (int kk = 0; kk < 4; ++kk) {
                const float4 alo = *(const float4*)(As + ((c << 2) + kk) * BR + ty8);
                const float4 ahi = *(const float4*)(As + ((c << 2) + kk) * BR + ty8 + 4);
#pragma unroll
                for (int jj = 0; jj < 8; ++jj) {
                    const float wv = (kk == 0) ? w[jj].x : (kk == 1) ? w[jj].y
                                   : (kk == 2) ? w[jj].z : w[jj].w;
                    acc[0][jj] = fmaf(alo.x, wv, acc[0][jj]);
                    acc[1][jj] = fmaf(alo.y, wv, acc[1][jj]);
                    acc[2][jj] = fmaf(alo.z, wv, acc[2][jj]);
                    acc[3][jj] = fmaf(alo.w, wv, acc[3][jj]);
                    acc[4][jj] = fmaf(ahi.x, wv, acc[4][jj]);
                    acc[5][jj] = fmaf(ahi.y, wv, acc[5][jj]);
                    acc[6][jj] = fmaf(ahi.z, wv, acc[6][jj]);
                    acc[7][jj] = fmaf(ahi.w, wv, acc[7][jj]);
                }
            }
        }
    }
    // ---- epilogue: bias + LayerNorm (reduce over the 16-lane tx group) + ReLU ----
    float bj[8], gj[8], btj[8];
#pragma unroll
    for (int jj = 0; jj < 8; ++jj) {
        int j = tx + (jj << 4);
        bj[jj] = bl[j]; gj[jj] = gamma[j]; btj[jj] = beta[j];
    }
#pragma unroll
    for (int rr = 0; rr < 8; ++rr) {
        float v[8]; float s1 = 0.f, s2 = 0.f;
#pragma unroll
        for (int jj = 0; jj < 8; ++jj) {
            v[jj] = acc[rr][jj] + bj[jj];
            s1 += v[jj];
            s2 = fmaf(v[jj], v[jj], s2);
        }
#pragma unroll
        for (int m = 1; m < 16; m <<= 1) {
            s1 += __shfl_xor(s1, m, 64);
            s2 += __shfl_xor(s2, m, 64);
        }
        const float mu = s1 * (1.f / 128.f);
        const float var = s2 * (1.f / 128.f) - mu * mu;
        const float rstd = rsqrtf(var + 1e-5f);
        const int orow = row0 + (ty << 3) + rr;
        if (orow < n) {
#pragma unroll
            for (int jj = 0; jj < 8; ++jj) {
                float o = (v[jj] - mu) * rstd * gj[jj] + btj[jj];
                y[(size_t)orow * D + tx + (jj << 4)] = fmaxf(o, 0.f);
            }
        }
    }
}

extern "C" void kernel_launch(void* const* d_in, const int* in_sizes, int n_in,
                              void* d_out, int out_size, void* d_ws, size_t ws_size,
                              hipStream_t stream) {
    const float* x   = (const float*)d_in[0];
    const int*   ei  = (const int*)d_in[1];
    const int E = in_sizes[1] / 2;
    const int n = in_sizes[0] / D;
    const int* srcp = ei;
    const int* dstp = ei + E;
    const float* Wl0 = (const float*)d_in[2];
    const float* bl0 = (const float*)d_in[3];
    const float* Wr0 = (const float*)d_in[4];
    const float* g0  = (const float*)d_in[5];
    const float* be0 = (const float*)d_in[6];
    const float* Wl1 = (const float*)d_in[7];
    const float* bl1 = (const float*)d_in[8];
    const float* Wr1 = (const float*)d_in[9];
    const float* g1  = (const float*)d_in[10];
    const float* be1 = (const float*)d_in[11];
    float* y = (float*)d_out;

    // workspace layout
    char* ws = (char*)d_ws;
    const size_t a = ((size_t)n * 4 + 255) & ~(size_t)255;
    int*   cnt    = (int*)ws;
    float* inv    = (float*)(ws + a);
    float* summed = (float*)(ws + 2 * a);
    const size_t need = 2 * a + (size_t)n * D * 4;
    if (ws_size < need) return;  // fail loudly via wrong output

    hipFuncSetAttribute((const void*)fused_kernel,
                        hipFuncAttributeMaxDynamicSharedMemorySize, LDS_BYTES);

    const int gE   = (E + 255) / 256;
    const int gN   = (n + 255) / 256;
    const int gSc  = (int)(((size_t)E * 32 + 255) / 256);
    const int gF   = (n + BR - 1) / BR;

    hipMemsetAsync(cnt, 0, (size_t)n * 4, stream);
    count_kernel<<<gE, 256, 0, stream>>>(dstp, cnt, E);
    inv_kernel<<<gN, 256, 0, stream>>>(cnt, inv, n);

    // layer 1 (output -> d_out, reused as layer-2 input)
    hipMemsetAsync(summed, 0, (size_t)n * D * 4, stream);
    scatter_kernel<<<gSc, 256, 0, stream>>>(x, srcp, dstp, summed, E);
    fused_kernel<<<gF, 256, LDS_BYTES, stream>>>(summed, inv, x,
                                                 Wl0, bl0, Wr0, g0, be0, y, n);
    // layer 2
    hipMemsetAsync(summed, 0, (size_t)n * D * 4, stream);
    scatter_kernel<<<gSc, 256, 0, stream>>>(y, srcp, dstp, summed, E);
    fused_kernel<<<gF, 256, LDS_BYTES, stream>>>(summed, inv, y,
                                                 Wl1, bl1, Wr1, g1, be1, y, n);
}

// Round 2
// 406.086 us; speedup vs baseline: 5.5460x; 5.5460x over previous
//
#include <hip/hip_runtime.h>

#define D 128
#define BR 128          // rows per block in fused kernel
#define WS_STRIDE 132   // padded W row stride (floats)
#define LDS_FLOATS (D * BR + D * WS_STRIDE)
#define LDS_BYTES (LDS_FLOATS * 4)

__global__ void count_kernel(const int* __restrict__ dst, int* __restrict__ cnt, int E) {
    int e = blockIdx.x * 256 + threadIdx.x;
    if (e < E) atomicAdd(&cnt[dst[e]], 1);
}

// single-block chunked exclusive scan: off[i] = cursor[i] = sum(cnt[0..i-1])
__global__ __launch_bounds__(1024, 1)
void scan_kernel(const int* __restrict__ cnt, int* __restrict__ off,
                 int* __restrict__ cursor, int n) {
    __shared__ int wsum[16];
    __shared__ int s_carry;
    const int tid = threadIdx.x;
    const int lane = tid & 63, wid = tid >> 6;
    if (tid == 0) s_carry = 0;
    __syncthreads();
    for (int base = 0; base < n; base += 1024) {
        int i = base + tid;
        int v = (i < n) ? cnt[i] : 0;
        int incl = v;
#pragma unroll
        for (int m = 1; m < 64; m <<= 1) {
            int t = __shfl_up(incl, m, 64);
            if (lane >= m) incl += t;
        }
        if (lane == 63) wsum[wid] = incl;
        __syncthreads();
        if (wid == 0 && lane < 16) {
            int ws = wsum[lane];
            int wincl = ws;
#pragma unroll
            for (int m = 1; m < 16; m <<= 1) {
                int t = __shfl_up(wincl, m, 16);
                if ((lane & 15) >= m) wincl += t;
            }
            wsum[lane] = wincl - ws;   // exclusive wave offset
        }
        __syncthreads();
        const int woff = wsum[wid];
        const int excl = s_carry + woff + incl - v;
        if (i < n) { off[i] = excl; cursor[i] = excl; }
        __syncthreads();
        if (tid == 1023) s_carry += woff + incl;
        __syncthreads();
    }
}

__global__ void fill_kernel(const int* __restrict__ src, const int* __restrict__ dst,
                            int* cursor, int* __restrict__ adj, int E) {
    int e = blockIdx.x * 256 + threadIdx.x;
    if (e < E) {
        int pos = atomicAdd(&cursor[dst[e]], 1);
        adj[pos] = src[e];
    }
}

// pull-mode mean aggregation: one wave per node, lane owns 2 columns
__global__ __launch_bounds__(256, 4)
void aggregate_kernel(const float* xin, const int* __restrict__ adj,
                      const int* __restrict__ off, const int* __restrict__ cnt,
                      float* __restrict__ agg, int n) {
    const int node = blockIdx.x * 4 + (threadIdx.x >> 6);
    if (node >= n) return;
    const int lane = threadIdx.x & 63;
    const int deg = cnt[node];
    const int o = off[node];
    const float* xp = xin + (size_t)(lane << 1);
    float2 acc = {0.f, 0.f};
    int k = 0;
    for (; k + 2 <= deg; k += 2) {
        const int s0 = adj[o + k], s1 = adj[o + k + 1];
        const float2 v0 = *(const float2*)(xp + (size_t)s0 * D);
        const float2 v1 = *(const float2*)(xp + (size_t)s1 * D);
        acc.x += v0.x + v1.x;
        acc.y += v0.y + v1.y;
    }
    if (k < deg) {
        const int s0 = adj[o + k];
        const float2 v0 = *(const float2*)(xp + (size_t)s0 * D);
        acc.x += v0.x;
        acc.y += v0.y;
    }
    const float s = 1.0f / (float)max(deg, 1);
    *(float2*)(agg + (size_t)node * D + (lane << 1)) = make_float2(acc.x * s, acc.y * s);
}

// fused: out = agg @ Wl^T + bl + xin @ Wr^T ; LayerNorm(gamma,beta); ReLU
__global__ __launch_bounds__(256, 1)
void fused_kernel(const float* __restrict__ agg, const float* xin,
                  const float* __restrict__ Wl, const float* __restrict__ bl,
                  const float* __restrict__ Wr,
                  const float* __restrict__ gamma, const float* __restrict__ beta,
                  float* y, int n) {
    extern __shared__ float lds[];
    float* As = lds;            // [128 k][BR rows] k-major
    float* Ws = lds + D * BR;   // [128 j][WS_STRIDE]
    const int tid = threadIdx.x;
    const int tx = tid & 15, ty = tid >> 4;
    const int row0 = blockIdx.x * BR;

    float acc[8][8];
#pragma unroll
    for (int a = 0; a < 8; ++a)
#pragma unroll
        for (int b = 0; b < 8; ++b) acc[a][b] = 0.f;

    const int r = tid >> 1;            // staging row 0..127
    const int h = (tid & 1) << 6;      // staging k-half 0/64
    const int srow = row0 + r;

    for (int pass = 0; pass < 2; ++pass) {
        const float* Wg = pass ? Wr : Wl;
        const float* Ag = pass ? xin : agg;
        if (pass) __syncthreads();
        for (int i = tid; i < (D * D) / 4; i += 256) {
            int f = i << 2;
            int j = f >> 7, k = f & (D - 1);
            float4 wv = *(const float4*)(Wg + f);
            *(float4*)(Ws + j * WS_STRIDE + k) = wv;
        }
#pragma unroll
        for (int i = 0; i < 16; ++i) {
            float4 v = {0.f, 0.f, 0.f, 0.f};
            if (srow < n) v = *(const float4*)(Ag + (size_t)srow * D + h + (i << 2));
            int k = h + (i << 2);
            As[(k + 0) * BR + r] = v.x;
            As[(k + 1) * BR + r] = v.y;
            As[(k + 2) * BR + r] = v.z;
            As[(k + 3) * BR + r] = v.w;
        }
        __syncthreads();
        const int ty8 = ty << 3;
        for (int c = 0; c < 32; ++c) {
            float4 w[8];
#pragma unroll
            for (int jj = 0; jj < 8; ++jj)
                w[jj] = *(const float4*)(Ws + (tx + (jj << 4)) * WS_STRIDE + (c << 2));
#pragma unroll
            for (int kk = 0; kk < 4; ++kk) {
                const float4 alo = *(const float4*)(As + ((c << 2) + kk) * BR + ty8);
                const float4 ahi = *(const float4*)(As + ((c << 2) + kk) * BR + ty8 + 4);
#pragma unroll
                for (int jj = 0; jj < 8; ++jj) {
                    const float wv = (kk == 0) ? w[jj].x : (kk == 1) ? w[jj].y
                                   : (kk == 2) ? w[jj].z : w[jj].w;
                    acc[0][jj] = fmaf(alo.x, wv, acc[0][jj]);
                    acc[1][jj] = fmaf(alo.y, wv, acc[1][jj]);
                    acc[2][jj] = fmaf(alo.z, wv, acc[2][jj]);
                    acc[3][jj] = fmaf(alo.w, wv, acc[3][jj]);
                    acc[4][jj] = fmaf(ahi.x, wv, acc[4][jj]);
                    acc[5][jj] = fmaf(ahi.y, wv, acc[5][jj]);
                    acc[6][jj] = fmaf(ahi.z, wv, acc[6][jj]);
                    acc[7][jj] = fmaf(ahi.w, wv, acc[7][jj]);
                }
            }
        }
    }
    float bj[8], gj[8], btj[8];
#pragma unroll
    for (int jj = 0; jj < 8; ++jj) {
        int j = tx + (jj << 4);
        bj[jj] = bl[j]; gj[jj] = gamma[j]; btj[jj] = beta[j];
    }
#pragma unroll
    for (int rr = 0; rr < 8; ++rr) {
        float v[8]; float s1 = 0.f, s2 = 0.f;
#pragma unroll
        for (int jj = 0; jj < 8; ++jj) {
            v[jj] = acc[rr][jj] + bj[jj];
            s1 += v[jj];
            s2 = fmaf(v[jj], v[jj], s2);
        }
#pragma unroll
        for (int m = 1; m < 16; m <<= 1) {
            s1 += __shfl_xor(s1, m, 64);
            s2 += __shfl_xor(s2, m, 64);
        }
        const float mu = s1 * (1.f / 128.f);
        const float var = s2 * (1.f / 128.f) - mu * mu;
        const float rstd = rsqrtf(var + 1e-5f);
        const int orow = row0 + (ty << 3) + rr;
        if (orow < n) {
#pragma unroll
            for (int jj = 0; jj < 8; ++jj) {
                float o = (v[jj] - mu) * rstd * gj[jj] + btj[jj];
                y[(size_t)orow * D + tx + (jj << 4)] = fmaxf(o, 0.f);
            }
        }
    }
}

extern "C" void kernel_launch(void* const* d_in, const int* in_sizes, int n_in,
                              void* d_out, int out_size, void* d_ws, size_t ws_size,
                              hipStream_t stream) {
    const float* x   = (const float*)d_in[0];
    const int*   ei  = (const int*)d_in[1];
    const int E = in_sizes[1] / 2;
    const int n = in_sizes[0] / D;
    const int* srcp = ei;
    const int* dstp = ei + E;
    const float* Wl0 = (const float*)d_in[2];
    const float* bl0 = (const float*)d_in[3];
    const float* Wr0 = (const float*)d_in[4];
    const float* g0  = (const float*)d_in[5];
    const float* be0 = (const float*)d_in[6];
    const float* Wl1 = (const float*)d_in[7];
    const float* bl1 = (const float*)d_in[8];
    const float* Wr1 = (const float*)d_in[9];
    const float* g1  = (const float*)d_in[10];
    const float* be1 = (const float*)d_in[11];
    float* y = (float*)d_out;

    // workspace layout: cnt | off | cursor | adj | agg
    char* ws = (char*)d_ws;
    const size_t aN = ((size_t)n * 4 + 255) & ~(size_t)255;
    const size_t aE = ((size_t)E * 4 + 255) & ~(size_t)255;
    int*   cnt    = (int*)ws;
    int*   off    = (int*)(ws + aN);
    int*   cursor = (int*)(ws + 2 * aN);
    int*   adj    = (int*)(ws + 3 * aN);
    float* agg    = (float*)(ws + 3 * aN + aE);
    const size_t need = 3 * aN + aE + (size_t)n * D * 4;
    if (ws_size < need) return;

    hipFuncSetAttribute((const void*)fused_kernel,
                        hipFuncAttributeMaxDynamicSharedMemorySize, LDS_BYTES);

    const int gE = (E + 255) / 256;
    const int gA = (n + 3) / 4;
    const int gF = (n + BR - 1) / BR;

    // CSR build (once; shared by both layers)
    hipMemsetAsync(cnt, 0, (size_t)n * 4, stream);
    count_kernel<<<gE, 256, 0, stream>>>(dstp, cnt, E);
    scan_kernel<<<1, 1024, 0, stream>>>(cnt, off, cursor, n);
    fill_kernel<<<gE, 256, 0, stream>>>(srcp, dstp, cursor, adj, E);

    // layer 1 (output -> d_out, reused as layer-2 input)
    aggregate_kernel<<<gA, 256, 0, stream>>>(x, adj, off, cnt, agg, n);
    fused_kernel<<<gF, 256, LDS_BYTES, stream>>>(agg, x, Wl0, bl0, Wr0, g0, be0, y, n);
    // layer 2
    aggregate_kernel<<<gA, 256, 0, stream>>>(y, adj, off, cnt, agg, n);
    fused_kernel<<<gF, 256, LDS_BYTES, stream>>>(agg, y, Wl1, bl1, Wr1, g1, be1, y, n);
}

// Round 3
// 245.087 us; speedup vs baseline: 9.1892x; 1.6569x over previous
//
#include <hip/hip_runtime.h>

#define D 128
#define BR 128   // rows per block in fused kernel

typedef _Float16 f16;
typedef f16 f16x8 __attribute__((ext_vector_type(8)));
typedef float f32x4 __attribute__((ext_vector_type(4)));

__global__ void count_kernel(const int* __restrict__ dst, int* __restrict__ cnt, int E) {
    int e = blockIdx.x * 256 + threadIdx.x;
    if (e < E) atomicAdd(&cnt[dst[e]], 1);
}

// single-block chunked exclusive scan: off[i] = cursor[i] = sum(cnt[0..i-1])
__global__ __launch_bounds__(1024, 1)
void scan_kernel(const int* __restrict__ cnt, int* __restrict__ off,
                 int* __restrict__ cursor, int n) {
    __shared__ int wsum[16];
    __shared__ int s_carry;
    const int tid = threadIdx.x;
    const int lane = tid & 63, wid = tid >> 6;
    if (tid == 0) s_carry = 0;
    __syncthreads();
    for (int base = 0; base < n; base += 1024) {
        int i = base + tid;
        int v = (i < n) ? cnt[i] : 0;
        int incl = v;
#pragma unroll
        for (int m = 1; m < 64; m <<= 1) {
            int t = __shfl_up(incl, m, 64);
            if (lane >= m) incl += t;
        }
        if (lane == 63) wsum[wid] = incl;
        __syncthreads();
        if (wid == 0 && lane < 16) {
            int ws = wsum[lane];
            int wincl = ws;
#pragma unroll
            for (int m = 1; m < 16; m <<= 1) {
                int t = __shfl_up(wincl, m, 16);
                if ((lane & 15) >= m) wincl += t;
            }
            wsum[lane] = wincl - ws;   // exclusive wave offset
        }
        __syncthreads();
        const int woff = wsum[wid];
        const int excl = s_carry + woff + incl - v;
        if (i < n) { off[i] = excl; cursor[i] = excl; }
        __syncthreads();
        if (tid == 1023) s_carry += woff + incl;
        __syncthreads();
    }
}

__global__ void fill_kernel(const int* __restrict__ src, const int* __restrict__ dst,
                            int* cursor, int* __restrict__ adj, int E) {
    int e = blockIdx.x * 256 + threadIdx.x;
    if (e < E) {
        int pos = atomicAdd(&cursor[dst[e]], 1);
        adj[pos] = src[e];
    }
}

// pull-mode mean aggregation: one wave per node, lane owns 2 columns
__global__ __launch_bounds__(256, 4)
void aggregate_kernel(const float* xin, const int* __restrict__ adj,
                      const int* __restrict__ off, const int* __restrict__ cnt,
                      float* __restrict__ agg, int n) {
    const int node = blockIdx.x * 4 + (threadIdx.x >> 6);
    if (node >= n) return;
    const int lane = threadIdx.x & 63;
    const int deg = cnt[node];
    const int o = off[node];
    const float* xp = xin + (size_t)(lane << 1);
    float2 acc = {0.f, 0.f};
    int k = 0;
    for (; k + 2 <= deg; k += 2) {
        const int s0 = adj[o + k], s1 = adj[o + k + 1];
        const float2 v0 = *(const float2*)(xp + (size_t)s0 * D);
        const float2 v1 = *(const float2*)(xp + (size_t)s1 * D);
        acc.x += v0.x + v1.x;
        acc.y += v0.y + v1.y;
    }
    if (k < deg) {
        const int s0 = adj[o + k];
        const float2 v0 = *(const float2*)(xp + (size_t)s0 * D);
        acc.x += v0.x;
        acc.y += v0.y;
    }
    const float s = 1.0f / (float)max(deg, 1);
    *(float2*)(agg + (size_t)node * D + (lane << 1)) = make_float2(acc.x * s, acc.y * s);
}

// stage a 128x128 f32 tile into LDS as f16, k-contiguous rows, XOR-swizzled
// granules: f16 element offset = row*128 + (k ^ ((row&7)*8)), 8 f16 per store.
__device__ __forceinline__ void stage_tile_f16(const float* __restrict__ src, f16* dst,
                                               int row0, int n, int tid) {
#pragma unroll
    for (int i = 0; i < 8; ++i) {
        const int flat = (i * 2048) + tid * 8;      // 8 floats per thread per iter
        const int row = flat >> 7;
        const int k = flat & 127;                   // multiple of 8
        float4 v0 = {0.f, 0.f, 0.f, 0.f}, v1 = {0.f, 0.f, 0.f, 0.f};
        if (row0 < 0 || row0 + row < n) {           // row0<0 => unguarded (weights)
            const float* p = src + (size_t)(row0 < 0 ? 0 : row0 + row) * D
                           + (row0 < 0 ? (size_t)flat : (size_t)k);
            v0 = *(const float4*)p;
            v1 = *(const float4*)(p + 4);
        }
        f16x8 h;
        h[0] = (f16)v0.x; h[1] = (f16)v0.y; h[2] = (f16)v0.z; h[3] = (f16)v0.w;
        h[4] = (f16)v1.x; h[5] = (f16)v1.y; h[6] = (f16)v1.z; h[7] = (f16)v1.w;
        *(f16x8*)(dst + row * D + (k ^ ((row & 7) * 8))) = h;
    }
}

// fused: out = agg @ Wl^T + bl + xin @ Wr^T ; LayerNorm(gamma,beta); ReLU
// MFMA f32_16x16x32_f16. 256 threads = 4 waves; wave w owns rows [w*32, w*32+32)
// of the 128-row tile and all 128 cols -> LN is wave-local.
__global__ __launch_bounds__(256, 2)
void fused_kernel(const float* __restrict__ agg, const float* xin,
                  const float* __restrict__ Wl, const float* __restrict__ bl,
                  const float* __restrict__ Wr,
                  const float* __restrict__ gamma, const float* __restrict__ beta,
                  float* y, int n) {
    extern __shared__ char lds_raw[];
    f16* As = (f16*)lds_raw;             // [128][128] swizzled
    f16* Ws = (f16*)(lds_raw + 32768);   // [128][128] swizzled
    const int tid = threadIdx.x;
    const int w = tid >> 6, l = tid & 63;
    const int c = l & 15, g = l >> 4;    // col-in-tile, k-group
    const int row0 = blockIdx.x * BR;

    f32x4 acc[2][8];
#pragma unroll
    for (int rt = 0; rt < 2; ++rt)
#pragma unroll
        for (int jt = 0; jt < 8; ++jt) acc[rt][jt] = (f32x4){0.f, 0.f, 0.f, 0.f};

    for (int pass = 0; pass < 2; ++pass) {
        if (pass) __syncthreads();
        stage_tile_f16(pass ? xin : agg, As, row0, n, tid);
        stage_tile_f16(pass ? Wr : Wl, Ws, -1, n, tid);
        __syncthreads();
#pragma unroll
        for (int ks = 0; ks < 4; ++ks) {
            const int ke = ks * 32 + g * 8;
            f16x8 av[2], bv[8];
#pragma unroll
            for (int rt = 0; rt < 2; ++rt) {
                const int ar = w * 32 + rt * 16 + c;
                av[rt] = *(const f16x8*)(As + ar * D + (ke ^ ((ar & 7) * 8)));
            }
#pragma unroll
            for (int jt = 0; jt < 8; ++jt) {
                const int br = jt * 16 + c;
                bv[jt] = *(const f16x8*)(Ws + br * D + (ke ^ ((br & 7) * 8)));
            }
#pragma unroll
            for (int rt = 0; rt < 2; ++rt)
#pragma unroll
                for (int jt = 0; jt < 8; ++jt)
                    acc[rt][jt] = __builtin_amdgcn_mfma_f32_16x16x32_f16(
                        av[rt], bv[jt], acc[rt][jt], 0, 0, 0);
        }
    }

    // epilogue: bias + LayerNorm + ReLU. C/D layout: col=l&15, row=(l>>4)*4+reg.
    float bj[8], gj[8], btj[8];
#pragma unroll
    for (int jt = 0; jt < 8; ++jt) {
        const int j = jt * 16 + c;
        bj[jt] = bl[j]; gj[jt] = gamma[j]; btj[jt] = beta[j];
    }
#pragma unroll
    for (int rt = 0; rt < 2; ++rt) {
#pragma unroll
        for (int reg = 0; reg < 4; ++reg) {
            float v[8]; float s1 = 0.f, s2 = 0.f;
#pragma unroll
            for (int jt = 0; jt < 8; ++jt) {
                v[jt] = acc[rt][jt][reg] + bj[jt];
                s1 += v[jt];
                s2 = fmaf(v[jt], v[jt], s2);
            }
#pragma unroll
            for (int m = 1; m < 16; m <<= 1) {
                s1 += __shfl_xor(s1, m, 64);
                s2 += __shfl_xor(s2, m, 64);
            }
            const float mu = s1 * (1.f / 128.f);
            const float var = s2 * (1.f / 128.f) - mu * mu;
            const float rstd = rsqrtf(var + 1e-5f);
            const int row = row0 + w * 32 + rt * 16 + g * 4 + reg;
            if (row < n) {
#pragma unroll
                for (int jt = 0; jt < 8; ++jt) {
                    const float o = (v[jt] - mu) * rstd * gj[jt] + btj[jt];
                    y[(size_t)row * D + jt * 16 + c] = fmaxf(o, 0.f);
                }
            }
        }
    }
}

extern "C" void kernel_launch(void* const* d_in, const int* in_sizes, int n_in,
                              void* d_out, int out_size, void* d_ws, size_t ws_size,
                              hipStream_t stream) {
    const float* x   = (const float*)d_in[0];
    const int*   ei  = (const int*)d_in[1];
    const int E = in_sizes[1] / 2;
    const int n = in_sizes[0] / D;
    const int* srcp = ei;
    const int* dstp = ei + E;
    const float* Wl0 = (const float*)d_in[2];
    const float* bl0 = (const float*)d_in[3];
    const float* Wr0 = (const float*)d_in[4];
    const float* g0  = (const float*)d_in[5];
    const float* be0 = (const float*)d_in[6];
    const float* Wl1 = (const float*)d_in[7];
    const float* bl1 = (const float*)d_in[8];
    const float* Wr1 = (const float*)d_in[9];
    const float* g1  = (const float*)d_in[10];
    const float* be1 = (const float*)d_in[11];
    float* y = (float*)d_out;

    // workspace layout: cnt | off | cursor | adj | agg
    char* ws = (char*)d_ws;
    const size_t aN = ((size_t)n * 4 + 255) & ~(size_t)255;
    const size_t aE = ((size_t)E * 4 + 255) & ~(size_t)255;
    int*   cnt    = (int*)ws;
    int*   off    = (int*)(ws + aN);
    int*   cursor = (int*)(ws + 2 * aN);
    int*   adj    = (int*)(ws + 3 * aN);
    float* agg    = (float*)(ws + 3 * aN + aE);
    const size_t need = 3 * aN + aE + (size_t)n * D * 4;
    if (ws_size < need) return;

    const int LDS_BYTES = 65536;
    hipFuncSetAttribute((const void*)fused_kernel,
                        hipFuncAttributeMaxDynamicSharedMemorySize, LDS_BYTES);

    const int gE = (E + 255) / 256;
    const int gA = (n + 3) / 4;
    const int gF = (n + BR - 1) / BR;

    // CSR build (once; shared by both layers)
    hipMemsetAsync(cnt, 0, (size_t)n * 4, stream);
    count_kernel<<<gE, 256, 0, stream>>>(dstp, cnt, E);
    scan_kernel<<<1, 1024, 0, stream>>>(cnt, off, cursor, n);
    fill_kernel<<<gE, 256, 0, stream>>>(srcp, dstp, cursor, adj, E);

    // layer 1 (output -> d_out, reused as layer-2 input)
    aggregate_kernel<<<gA, 256, 0, stream>>>(x, adj, off, cnt, agg, n);
    fused_kernel<<<gF, 256, LDS_BYTES, stream>>>(agg, x, Wl0, bl0, Wr0, g0, be0, y, n);
    // layer 2
    aggregate_kernel<<<gA, 256, 0, stream>>>(y, adj, off, cnt, agg, n);
    fused_kernel<<<gF, 256, LDS_BYTES, stream>>>(agg, y, Wl1, bl1, Wr1, g1, be1, y, n);
}

// Round 4
// 175.422 us; speedup vs baseline: 12.8385x; 1.3971x over previous
//
#include <hip/hip_runtime.h>

#define D 128
#define BR 128   // rows per block in fused kernel

typedef _Float16 f16;
typedef f16 f16x2 __attribute__((ext_vector_type(2)));
typedef f16 f16x8 __attribute__((ext_vector_type(8)));
typedef float f32x4 __attribute__((ext_vector_type(4)));

__global__ void convert_kernel(const float* __restrict__ src, f16* __restrict__ dst,
                               int count8) {
    const int i = blockIdx.x * 256 + threadIdx.x;
    if (i >= count8) return;
    const float4 v0 = *(const float4*)(src + (size_t)i * 8);
    const float4 v1 = *(const float4*)(src + (size_t)i * 8 + 4);
    f16x8 h;
    h[0] = (f16)v0.x; h[1] = (f16)v0.y; h[2] = (f16)v0.z; h[3] = (f16)v0.w;
    h[4] = (f16)v1.x; h[5] = (f16)v1.y; h[6] = (f16)v1.z; h[7] = (f16)v1.w;
    *(f16x8*)(dst + (size_t)i * 8) = h;
}

__global__ void count_kernel(const int* __restrict__ dst, int* __restrict__ cnt, int E) {
    int e = blockIdx.x * 256 + threadIdx.x;
    if (e < E) atomicAdd(&cnt[dst[e]], 1);
}

// ---- 3-phase exclusive scan over cnt[0..n) ----
// phase 1: per-block (1024 elems) sums
__global__ __launch_bounds__(256)
void scan1_kernel(const int* __restrict__ cnt, int* __restrict__ part, int n) {
    const int t = threadIdx.x;
    const int i0 = blockIdx.x * 1024 + t * 4;
    int s = 0;
#pragma unroll
    for (int j = 0; j < 4; ++j) { int i = i0 + j; if (i < n) s += cnt[i]; }
#pragma unroll
    for (int m = 1; m < 64; m <<= 1) s += __shfl_xor(s, m, 64);
    __shared__ int ws[4];
    if ((t & 63) == 0) ws[t >> 6] = s;
    __syncthreads();
    if (t == 0) part[blockIdx.x] = ws[0] + ws[1] + ws[2] + ws[3];
}

// phase 2: single-wave exclusive scan of partials (carry loop)
__global__ void scan2_kernel(int* part, int nb) {
    const int t = threadIdx.x;  // 64 threads
    int carry = 0;
    for (int base = 0; base < nb; base += 64) {
        const int i = base + t;
        int v = (i < nb) ? part[i] : 0;
        int incl = v;
#pragma unroll
        for (int m = 1; m < 64; m <<= 1) {
            int u = __shfl_up(incl, m, 64);
            if (t >= m) incl += u;
        }
        if (i < nb) part[i] = carry + incl - v;
        carry += __shfl(incl, 63, 64);
    }
}

// phase 3: per-block rescan + apply block offset -> off, cursor
__global__ __launch_bounds__(256)
void scan3_kernel(const int* __restrict__ cnt, const int* __restrict__ part,
                  int* __restrict__ off, int* __restrict__ cursor, int n) {
    const int t = threadIdx.x;
    const int lane = t & 63, wid = t >> 6;
    const int i0 = blockIdx.x * 1024 + t * 4;
    int v[4]; int s = 0;
#pragma unroll
    for (int j = 0; j < 4; ++j) { v[j] = (i0 + j < n) ? cnt[i0 + j] : 0; s += v[j]; }
    int incl = s;
#pragma unroll
    for (int m = 1; m < 64; m <<= 1) {
        int u = __shfl_up(incl, m, 64);
        if (lane >= m) incl += u;
    }
    __shared__ int ws[4];
    if (lane == 63) ws[wid] = incl;
    __syncthreads();
    int woff = 0;
#pragma unroll
    for (int k = 0; k < 4; ++k) woff += (k < wid) ? ws[k] : 0;
    int run = part[blockIdx.x] + woff + incl - s;
#pragma unroll
    for (int j = 0; j < 4; ++j) {
        if (i0 + j < n) { off[i0 + j] = run; cursor[i0 + j] = run; run += v[j]; }
    }
}

__global__ void fill_kernel(const int* __restrict__ src, const int* __restrict__ dst,
                            int* cursor, int* __restrict__ adj, int E) {
    int e = blockIdx.x * 256 + threadIdx.x;
    if (e < E) {
        int pos = atomicAdd(&cursor[dst[e]], 1);
        adj[pos] = src[e];
    }
}

// pull-mode mean aggregation, f16 in / f16 out, f32 accumulate.
// one wave per node, lane owns 2 columns (4B loads), 4-neighbor ILP.
__global__ __launch_bounds__(256, 4)
void aggregate_kernel(const f16* xin, const int* __restrict__ adj,
                      const int* __restrict__ off, const int* __restrict__ cnt,
                      f16* __restrict__ agg, int n) {
    const int node = blockIdx.x * 4 + (threadIdx.x >> 6);
    if (node >= n) return;
    const int lane = threadIdx.x & 63;
    const int deg = cnt[node];
    const int o = off[node];
    const f16* xp = xin + (lane << 1);
    float ax = 0.f, ay = 0.f;
    int k = 0;
    for (; k + 4 <= deg; k += 4) {
        const int s0 = adj[o + k],     s1 = adj[o + k + 1];
        const int s2 = adj[o + k + 2], s3 = adj[o + k + 3];
        const f16x2 v0 = *(const f16x2*)(xp + (size_t)s0 * D);
        const f16x2 v1 = *(const f16x2*)(xp + (size_t)s1 * D);
        const f16x2 v2 = *(const f16x2*)(xp + (size_t)s2 * D);
        const f16x2 v3 = *(const f16x2*)(xp + (size_t)s3 * D);
        ax += (float)v0[0] + (float)v1[0] + (float)v2[0] + (float)v3[0];
        ay += (float)v0[1] + (float)v1[1] + (float)v2[1] + (float)v3[1];
    }
    for (; k < deg; ++k) {
        const int s0 = adj[o + k];
        const f16x2 v0 = *(const f16x2*)(xp + (size_t)s0 * D);
        ax += (float)v0[0];
        ay += (float)v0[1];
    }
    const float s = 1.0f / (float)max(deg, 1);
    f16x2 r; r[0] = (f16)(ax * s); r[1] = (f16)(ay * s);
    *(f16x2*)(agg + (size_t)node * D + (lane << 1)) = r;
}

// stage a 128x128 f16 tile (row-guarded) into LDS, XOR-swizzled granules
__device__ __forceinline__ void stage_tile_h(const f16* src, f16* dst,
                                             int row0, int n, int tid) {
#pragma unroll
    for (int i = 0; i < 8; ++i) {
        const int flat = i * 2048 + tid * 8;
        const int row = flat >> 7;
        const int k = flat & 127;
        f16x8 h = {};
        if (row0 + row < n) h = *(const f16x8*)(src + (size_t)(row0 + row) * D + k);
        *(f16x8*)(dst + row * D + (k ^ ((row & 7) * 8))) = h;
    }
}

// stage a 128x128 f32 weight matrix into LDS as f16, XOR-swizzled
__device__ __forceinline__ void stage_w(const float* __restrict__ src, f16* dst, int tid) {
#pragma unroll
    for (int i = 0; i < 8; ++i) {
        const int flat = i * 2048 + tid * 8;
        const int row = flat >> 7;
        const int k = flat & 127;
        const float4 v0 = *(const float4*)(src + flat);
        const float4 v1 = *(const float4*)(src + flat + 4);
        f16x8 h;
        h[0] = (f16)v0.x; h[1] = (f16)v0.y; h[2] = (f16)v0.z; h[3] = (f16)v0.w;
        h[4] = (f16)v1.x; h[5] = (f16)v1.y; h[6] = (f16)v1.z; h[7] = (f16)v1.w;
        *(f16x8*)(dst + row * D + (k ^ ((row & 7) * 8))) = h;
    }
}

// fused: out = agg @ Wl^T + bl + xin @ Wr^T ; LayerNorm ; ReLU
// LAST=false: write f16 into yh (may alias xinh; per-block rows read before write).
// LAST=true : write f32 into yf (final output).
template <bool LAST>
__global__ __launch_bounds__(256, 2)
void fused_kernel(const f16* __restrict__ aggh, const f16* xinh,
                  const float* __restrict__ Wl, const float* __restrict__ bl,
                  const float* __restrict__ Wr,
                  const float* __restrict__ gamma, const float* __restrict__ beta,
                  f16* yh, float* __restrict__ yf, int n) {
    extern __shared__ char lds_raw[];
    f16* As = (f16*)lds_raw;             // [128][128] swizzled
    f16* Ws = (f16*)(lds_raw + 32768);   // [128][128] swizzled
    const int tid = threadIdx.x;
    const int w = tid >> 6, l = tid & 63;
    const int c = l & 15, g = l >> 4;
    const int row0 = blockIdx.x * BR;

    f32x4 acc[2][8];
#pragma unroll
    for (int rt = 0; rt < 2; ++rt)
#pragma unroll
        for (int jt = 0; jt < 8; ++jt) acc[rt][jt] = (f32x4){0.f, 0.f, 0.f, 0.f};

    for (int pass = 0; pass < 2; ++pass) {
        if (pass) __syncthreads();
        stage_tile_h(pass ? xinh : aggh, As, row0, n, tid);
        stage_w(pass ? Wr : Wl, Ws, tid);
        __syncthreads();
#pragma unroll
        for (int ks = 0; ks < 4; ++ks) {
            const int ke = ks * 32 + g * 8;
            f16x8 av[2], bv[8];
#pragma unroll
            for (int rt = 0; rt < 2; ++rt) {
                const int ar = w * 32 + rt * 16 + c;
                av[rt] = *(const f16x8*)(As + ar * D + (ke ^ ((ar & 7) * 8)));
            }
#pragma unroll
            for (int jt = 0; jt < 8; ++jt) {
                const int br = jt * 16 + c;
                bv[jt] = *(const f16x8*)(Ws + br * D + (ke ^ ((br & 7) * 8)));
            }
#pragma unroll
            for (int rt = 0; rt < 2; ++rt)
#pragma unroll
                for (int jt = 0; jt < 8; ++jt)
                    acc[rt][jt] = __builtin_amdgcn_mfma_f32_16x16x32_f16(
                        av[rt], bv[jt], acc[rt][jt], 0, 0, 0);
        }
    }

    // epilogue: bias + LayerNorm + ReLU. C/D layout: col=l&15, row=(l>>4)*4+reg.
    float bj[8], gj[8], btj[8];
#pragma unroll
    for (int jt = 0; jt < 8; ++jt) {
        const int j = jt * 16 + c;
        bj[jt] = bl[j]; gj[jt] = gamma[j]; btj[jt] = beta[j];
    }
#pragma unroll
    for (int rt = 0; rt < 2; ++rt) {
#pragma unroll
        for (int reg = 0; reg < 4; ++reg) {
            float v[8]; float s1 = 0.f, s2 = 0.f;
#pragma unroll
            for (int jt = 0; jt < 8; ++jt) {
                v[jt] = acc[rt][jt][reg] + bj[jt];
                s1 += v[jt];
                s2 = fmaf(v[jt], v[jt], s2);
            }
#pragma unroll
            for (int m = 1; m < 16; m <<= 1) {
                s1 += __shfl_xor(s1, m, 64);
                s2 += __shfl_xor(s2, m, 64);
            }
            const float mu = s1 * (1.f / 128.f);
            const float var = s2 * (1.f / 128.f) - mu * mu;
            const float rstd = rsqrtf(var + 1e-5f);
            const int row = row0 + w * 32 + rt * 16 + g * 4 + reg;
            if (row < n) {
#pragma unroll
                for (int jt = 0; jt < 8; ++jt) {
                    const float o = fmaxf((v[jt] - mu) * rstd * gj[jt] + btj[jt], 0.f);
                    if (LAST) yf[(size_t)row * D + jt * 16 + c] = o;
                    else      yh[(size_t)row * D + jt * 16 + c] = (f16)o;
                }
            }
        }
    }
}

extern "C" void kernel_launch(void* const* d_in, const int* in_sizes, int n_in,
                              void* d_out, int out_size, void* d_ws, size_t ws_size,
                              hipStream_t stream) {
    const float* x   = (const float*)d_in[0];
    const int*   ei  = (const int*)d_in[1];
    const int E = in_sizes[1] / 2;
    const int n = in_sizes[0] / D;
    const int* srcp = ei;
    const int* dstp = ei + E;
    const float* Wl0 = (const float*)d_in[2];
    const float* bl0 = (const float*)d_in[3];
    const float* Wr0 = (const float*)d_in[4];
    const float* g0  = (const float*)d_in[5];
    const float* be0 = (const float*)d_in[6];
    const float* Wl1 = (const float*)d_in[7];
    const float* bl1 = (const float*)d_in[8];
    const float* Wr1 = (const float*)d_in[9];
    const float* g1  = (const float*)d_in[10];
    const float* be1 = (const float*)d_in[11];
    float* y = (float*)d_out;

    // workspace: cnt | off | cursor | part | adj | aggh | xh(=y1h)
    char* ws = (char*)d_ws;
    const size_t aN = ((size_t)n * 4 + 255) & ~(size_t)255;
    const size_t aE = ((size_t)E * 4 + 255) & ~(size_t)255;
    const size_t aP = 4096;
    const size_t aH = ((size_t)n * D * 2 + 255) & ~(size_t)255;
    int* cnt    = (int*)ws;
    int* off    = (int*)(ws + aN);
    int* cursor = (int*)(ws + 2 * aN);
    int* part   = (int*)(ws + 3 * aN);
    int* adj    = (int*)(ws + 3 * aN + aP);
    f16* aggh   = (f16*)(ws + 3 * aN + aP + aE);
    f16* xh     = (f16*)(ws + 3 * aN + aP + aE + aH);
    const size_t need = 3 * aN + aP + aE + 2 * aH;
    if (ws_size < need) return;

    const int LDS_BYTES = 65536;
    hipFuncSetAttribute((const void*)fused_kernel<false>,
                        hipFuncAttributeMaxDynamicSharedMemorySize, LDS_BYTES);
    hipFuncSetAttribute((const void*)fused_kernel<true>,
                        hipFuncAttributeMaxDynamicSharedMemorySize, LDS_BYTES);

    const int gE = (E + 255) / 256;
    const int gA = (n + 3) / 4;
    const int gF = (n + BR - 1) / BR;
    const int nb = (n + 1023) / 1024;
    const int gC = ((n * D / 8) + 255) / 256;

    // CSR build + x->f16 (once)
    hipMemsetAsync(cnt, 0, (size_t)n * 4, stream);
    convert_kernel<<<gC, 256, 0, stream>>>(x, xh, n * D / 8);
    count_kernel<<<gE, 256, 0, stream>>>(dstp, cnt, E);
    scan1_kernel<<<nb, 256, 0, stream>>>(cnt, part, n);
    scan2_kernel<<<1, 64, 0, stream>>>(part, nb);
    scan3_kernel<<<nb, 256, 0, stream>>>(cnt, part, off, cursor, n);
    fill_kernel<<<gE, 256, 0, stream>>>(srcp, dstp, cursor, adj, E);

    // layer 1: aggregate(xh) -> aggh ; fused writes f16 y1 over xh (row-aliased safe)
    aggregate_kernel<<<gA, 256, 0, stream>>>(xh, adj, off, cnt, aggh, n);
    fused_kernel<false><<<gF, 256, LDS_BYTES, stream>>>(aggh, xh, Wl0, bl0, Wr0,
                                                        g0, be0, xh, nullptr, n);
    // layer 2: aggregate(y1h=xh) -> aggh ; fused writes f32 d_out
    aggregate_kernel<<<gA, 256, 0, stream>>>(xh, adj, off, cnt, aggh, n);
    fused_kernel<true><<<gF, 256, LDS_BYTES, stream>>>(aggh, xh, Wl1, bl1, Wr1,
                                                       g1, be1, nullptr, y, n);
}

// Round 5
// 164.527 us; speedup vs baseline: 13.6887x; 1.0662x over previous
//
#include <hip/hip_runtime.h>

#define D 128
#define BR 128   // rows per block in fused kernel

typedef _Float16 f16;
typedef f16 f16x4 __attribute__((ext_vector_type(4)));
typedef f16 f16x8 __attribute__((ext_vector_type(8)));
typedef float f32x4 __attribute__((ext_vector_type(4)));

__global__ void zero_kernel(int4* __restrict__ p, int count4) {
    const int i = blockIdx.x * 256 + threadIdx.x;
    if (i < count4) p[i] = make_int4(0, 0, 0, 0);
}

__global__ void convert_kernel(const float* __restrict__ src, f16* __restrict__ dst,
                               int count8) {
    const int i = blockIdx.x * 256 + threadIdx.x;
    if (i >= count8) return;
    const float4 v0 = *(const float4*)(src + (size_t)i * 8);
    const float4 v1 = *(const float4*)(src + (size_t)i * 8 + 4);
    f16x8 h;
    h[0] = (f16)v0.x; h[1] = (f16)v0.y; h[2] = (f16)v0.z; h[3] = (f16)v0.w;
    h[4] = (f16)v1.x; h[5] = (f16)v1.y; h[6] = (f16)v1.z; h[7] = (f16)v1.w;
    *(f16x8*)(dst + (size_t)i * 8) = h;
}

__global__ void count_kernel(const int* __restrict__ dst, int* __restrict__ cnt, int E) {
    int e = blockIdx.x * 256 + threadIdx.x;
    if (e < E) atomicAdd(&cnt[dst[e]], 1);
}

// ---- 3-phase exclusive scan over cnt[0..n) ----
__global__ __launch_bounds__(256)
void scan1_kernel(const int* __restrict__ cnt, int* __restrict__ part, int n) {
    const int t = threadIdx.x;
    const int i0 = blockIdx.x * 1024 + t * 4;
    int s = 0;
#pragma unroll
    for (int j = 0; j < 4; ++j) { int i = i0 + j; if (i < n) s += cnt[i]; }
#pragma unroll
    for (int m = 1; m < 64; m <<= 1) s += __shfl_xor(s, m, 64);
    __shared__ int ws[4];
    if ((t & 63) == 0) ws[t >> 6] = s;
    __syncthreads();
    if (t == 0) part[blockIdx.x] = ws[0] + ws[1] + ws[2] + ws[3];
}

__global__ void scan2_kernel(int* part, int nb) {
    const int t = threadIdx.x;  // 64 threads
    int carry = 0;
    for (int base = 0; base < nb; base += 64) {
        const int i = base + t;
        int v = (i < nb) ? part[i] : 0;
        int incl = v;
#pragma unroll
        for (int m = 1; m < 64; m <<= 1) {
            int u = __shfl_up(incl, m, 64);
            if (t >= m) incl += u;
        }
        if (i < nb) part[i] = carry + incl - v;
        carry += __shfl(incl, 63, 64);
    }
}

__global__ __launch_bounds__(256)
void scan3_kernel(const int* __restrict__ cnt, const int* __restrict__ part,
                  int* __restrict__ off, int* __restrict__ cursor, int n) {
    const int t = threadIdx.x;
    const int lane = t & 63, wid = t >> 6;
    const int i0 = blockIdx.x * 1024 + t * 4;
    int v[4]; int s = 0;
#pragma unroll
    for (int j = 0; j < 4; ++j) { v[j] = (i0 + j < n) ? cnt[i0 + j] : 0; s += v[j]; }
    int incl = s;
#pragma unroll
    for (int m = 1; m < 64; m <<= 1) {
        int u = __shfl_up(incl, m, 64);
        if (lane >= m) incl += u;
    }
    __shared__ int ws[4];
    if (lane == 63) ws[wid] = incl;
    __syncthreads();
    int woff = 0;
#pragma unroll
    for (int k = 0; k < 4; ++k) woff += (k < wid) ? ws[k] : 0;
    int run = part[blockIdx.x] + woff + incl - s;
#pragma unroll
    for (int j = 0; j < 4; ++j) {
        if (i0 + j < n) { off[i0 + j] = run; cursor[i0 + j] = run; run += v[j]; }
    }
}

__global__ void fill_kernel(const int* __restrict__ src, const int* __restrict__ dst,
                            int* cursor, int* __restrict__ adj, int E) {
    int e = blockIdx.x * 256 + threadIdx.x;
    if (e < E) {
        int pos = atomicAdd(&cursor[dst[e]], 1);
        adj[pos] = src[e];
    }
}

// pull-mode mean aggregation, f16 in/out, f32 accumulate.
// 2 nodes per wave (half-wave of 32 lanes each), lane owns 4 cols (8B loads),
// 4-neighbor ILP. 8 nodes per 256-thread block.
__global__ __launch_bounds__(256, 4)
void aggregate_kernel(const f16* xin, const int* __restrict__ adj,
                      const int* __restrict__ off, const int* __restrict__ cnt,
                      f16* __restrict__ agg, int n) {
    const int node = blockIdx.x * 8 + (threadIdx.x >> 5);
    if (node >= n) return;
    const int lane = threadIdx.x & 31;
    const int deg = cnt[node];
    const int o = off[node];
    const f16* xp = xin + (lane << 2);
    float a0 = 0.f, a1 = 0.f, a2 = 0.f, a3 = 0.f;
    int k = 0;
    for (; k + 4 <= deg; k += 4) {
        const int s0 = adj[o + k],     s1 = adj[o + k + 1];
        const int s2 = adj[o + k + 2], s3 = adj[o + k + 3];
        const f16x4 v0 = *(const f16x4*)(xp + (size_t)s0 * D);
        const f16x4 v1 = *(const f16x4*)(xp + (size_t)s1 * D);
        const f16x4 v2 = *(const f16x4*)(xp + (size_t)s2 * D);
        const f16x4 v3 = *(const f16x4*)(xp + (size_t)s3 * D);
        a0 += (float)v0[0] + (float)v1[0] + (float)v2[0] + (float)v3[0];
        a1 += (float)v0[1] + (float)v1[1] + (float)v2[1] + (float)v3[1];
        a2 += (float)v0[2] + (float)v1[2] + (float)v2[2] + (float)v3[2];
        a3 += (float)v0[3] + (float)v1[3] + (float)v2[3] + (float)v3[3];
    }
    for (; k < deg; ++k) {
        const int s0 = adj[o + k];
        const f16x4 v0 = *(const f16x4*)(xp + (size_t)s0 * D);
        a0 += (float)v0[0]; a1 += (float)v0[1]; a2 += (float)v0[2]; a3 += (float)v0[3];
    }
    const float s = 1.0f / (float)max(deg, 1);
    f16x4 r;
    r[0] = (f16)(a0 * s); r[1] = (f16)(a1 * s);
    r[2] = (f16)(a2 * s); r[3] = (f16)(a3 * s);
    *(f16x4*)(agg + (size_t)node * D + (lane << 2)) = r;
}

// stage a 128x128 f16 tile (row-guarded) into LDS, XOR-swizzled granules
__device__ __forceinline__ void stage_tile_h(const f16* src, f16* dst,
                                             int row0, int n, int tid) {
#pragma unroll
    for (int i = 0; i < 8; ++i) {
        const int flat = i * 2048 + tid * 8;
        const int row = flat >> 7;
        const int k = flat & 127;
        f16x8 h = {};
        if (row0 + row < n) h = *(const f16x8*)(src + (size_t)(row0 + row) * D + k);
        *(f16x8*)(dst + row * D + (k ^ ((row & 7) * 8))) = h;
    }
}

// stage a 128x128 f32 weight matrix into LDS as f16, XOR-swizzled
__device__ __forceinline__ void stage_w(const float* __restrict__ src, f16* dst, int tid) {
#pragma unroll
    for (int i = 0; i < 8; ++i) {
        const int flat = i * 2048 + tid * 8;
        const int row = flat >> 7;
        const int k = flat & 127;
        const float4 v0 = *(const float4*)(src + flat);
        const float4 v1 = *(const float4*)(src + flat + 4);
        f16x8 h;
        h[0] = (f16)v0.x; h[1] = (f16)v0.y; h[2] = (f16)v0.z; h[3] = (f16)v0.w;
        h[4] = (f16)v1.x; h[5] = (f16)v1.y; h[6] = (f16)v1.z; h[7] = (f16)v1.w;
        *(f16x8*)(dst + row * D + (k ^ ((row & 7) * 8))) = h;
    }
}

// fused: out = agg @ Wl^T + bl + xin @ Wr^T ; LayerNorm ; ReLU
template <bool LAST>
__global__ __launch_bounds__(256, 2)
void fused_kernel(const f16* __restrict__ aggh, const f16* xinh,
                  const float* __restrict__ Wl, const float* __restrict__ bl,
                  const float* __restrict__ Wr,
                  const float* __restrict__ gamma, const float* __restrict__ beta,
                  f16* yh, float* __restrict__ yf, int n) {
    extern __shared__ char lds_raw[];
    f16* As = (f16*)lds_raw;             // [128][128] swizzled
    f16* Ws = (f16*)(lds_raw + 32768);   // [128][128] swizzled
    const int tid = threadIdx.x;
    const int w = tid >> 6, l = tid & 63;
    const int c = l & 15, g = l >> 4;
    const int row0 = blockIdx.x * BR;

    f32x4 acc[2][8];
#pragma unroll
    for (int rt = 0; rt < 2; ++rt)
#pragma unroll
        for (int jt = 0; jt < 8; ++jt) acc[rt][jt] = (f32x4){0.f, 0.f, 0.f, 0.f};

    for (int pass = 0; pass < 2; ++pass) {
        if (pass) __syncthreads();
        stage_tile_h(pass ? xinh : aggh, As, row0, n, tid);
        stage_w(pass ? Wr : Wl, Ws, tid);
        __syncthreads();
#pragma unroll
        for (int ks = 0; ks < 4; ++ks) {
            const int ke = ks * 32 + g * 8;
            f16x8 av[2], bv[8];
#pragma unroll
            for (int rt = 0; rt < 2; ++rt) {
                const int ar = w * 32 + rt * 16 + c;
                av[rt] = *(const f16x8*)(As + ar * D + (ke ^ ((ar & 7) * 8)));
            }
#pragma unroll
            for (int jt = 0; jt < 8; ++jt) {
                const int br = jt * 16 + c;
                bv[jt] = *(const f16x8*)(Ws + br * D + (ke ^ ((br & 7) * 8)));
            }
#pragma unroll
            for (int rt = 0; rt < 2; ++rt)
#pragma unroll
                for (int jt = 0; jt < 8; ++jt)
                    acc[rt][jt] = __builtin_amdgcn_mfma_f32_16x16x32_f16(
                        av[rt], bv[jt], acc[rt][jt], 0, 0, 0);
        }
    }

    // epilogue: bias + LayerNorm + ReLU. C/D layout: col=l&15, row=(l>>4)*4+reg.
    float bj[8], gj[8], btj[8];
#pragma unroll
    for (int jt = 0; jt < 8; ++jt) {
        const int j = jt * 16 + c;
        bj[jt] = bl[j]; gj[jt] = gamma[j]; btj[jt] = beta[j];
    }
#pragma unroll
    for (int rt = 0; rt < 2; ++rt) {
#pragma unroll
        for (int reg = 0; reg < 4; ++reg) {
            float v[8]; float s1 = 0.f, s2 = 0.f;
#pragma unroll
            for (int jt = 0; jt < 8; ++jt) {
                v[jt] = acc[rt][jt][reg] + bj[jt];
                s1 += v[jt];
                s2 = fmaf(v[jt], v[jt], s2);
            }
#pragma unroll
            for (int m = 1; m < 16; m <<= 1) {
                s1 += __shfl_xor(s1, m, 64);
                s2 += __shfl_xor(s2, m, 64);
            }
            const float mu = s1 * (1.f / 128.f);
            const float var = s2 * (1.f / 128.f) - mu * mu;
            const float rstd = rsqrtf(var + 1e-5f);
            const int row = row0 + w * 32 + rt * 16 + g * 4 + reg;
            if (row < n) {
#pragma unroll
                for (int jt = 0; jt < 8; ++jt) {
                    const float o = fmaxf((v[jt] - mu) * rstd * gj[jt] + btj[jt], 0.f);
                    if (LAST) yf[(size_t)row * D + jt * 16 + c] = o;
                    else      yh[(size_t)row * D + jt * 16 + c] = (f16)o;
                }
            }
        }
    }
}

extern "C" void kernel_launch(void* const* d_in, const int* in_sizes, int n_in,
                              void* d_out, int out_size, void* d_ws, size_t ws_size,
                              hipStream_t stream) {
    const float* x   = (const float*)d_in[0];
    const int*   ei  = (const int*)d_in[1];
    const int E = in_sizes[1] / 2;
    const int n = in_sizes[0] / D;
    const int* srcp = ei;
    const int* dstp = ei + E;
    const float* Wl0 = (const float*)d_in[2];
    const float* bl0 = (const float*)d_in[3];
    const float* Wr0 = (const float*)d_in[4];
    const float* g0  = (const float*)d_in[5];
    const float* be0 = (const float*)d_in[6];
    const float* Wl1 = (const float*)d_in[7];
    const float* bl1 = (const float*)d_in[8];
    const float* Wr1 = (const float*)d_in[9];
    const float* g1  = (const float*)d_in[10];
    const float* be1 = (const float*)d_in[11];
    float* y = (float*)d_out;

    // workspace: cnt | off | cursor | part | adj | aggh | xh(=y1h)
    char* ws = (char*)d_ws;
    const size_t aN = ((size_t)n * 4 + 255) & ~(size_t)255;
    const size_t aE = ((size_t)E * 4 + 255) & ~(size_t)255;
    const size_t aP = 4096;
    const size_t aH = ((size_t)n * D * 2 + 255) & ~(size_t)255;
    int* cnt    = (int*)ws;
    int* off    = (int*)(ws + aN);
    int* cursor = (int*)(ws + 2 * aN);
    int* part   = (int*)(ws + 3 * aN);
    int* adj    = (int*)(ws + 3 * aN + aP);
    f16* aggh   = (f16*)(ws + 3 * aN + aP + aE);
    f16* xh     = (f16*)(ws + 3 * aN + aP + aE + aH);
    const size_t need = 3 * aN + aP + aE + 2 * aH;
    if (ws_size < need) return;

    const int LDS_BYTES = 65536;
    hipFuncSetAttribute((const void*)fused_kernel<false>,
                        hipFuncAttributeMaxDynamicSharedMemorySize, LDS_BYTES);
    hipFuncSetAttribute((const void*)fused_kernel<true>,
                        hipFuncAttributeMaxDynamicSharedMemorySize, LDS_BYTES);

    const int gE = (E + 255) / 256;
    const int gA = (n + 7) / 8;
    const int gF = (n + BR - 1) / BR;
    const int nb = (n + 1023) / 1024;
    const int gC = ((n * D / 8) + 255) / 256;
    const int gZ = ((n + 3) / 4 + 255) / 256;

    // CSR build + x->f16 (once)
    zero_kernel<<<gZ, 256, 0, stream>>>((int4*)cnt, (n + 3) / 4);
    convert_kernel<<<gC, 256, 0, stream>>>(x, xh, n * D / 8);
    count_kernel<<<gE, 256, 0, stream>>>(dstp, cnt, E);
    scan1_kernel<<<nb, 256, 0, stream>>>(cnt, part, n);
    scan2_kernel<<<1, 64, 0, stream>>>(part, nb);
    scan3_kernel<<<nb, 256, 0, stream>>>(cnt, part, off, cursor, n);
    fill_kernel<<<gE, 256, 0, stream>>>(srcp, dstp, cursor, adj, E);

    // layer 1: aggregate(xh) -> aggh ; fused writes f16 y1 over xh (row-aliased safe)
    aggregate_kernel<<<gA, 256, 0, stream>>>(xh, adj, off, cnt, aggh, n);
    fused_kernel<false><<<gF, 256, LDS_BYTES, stream>>>(aggh, xh, Wl0, bl0, Wr0,
                                                        g0, be0, xh, nullptr, n);
    // layer 2: aggregate(y1h=xh) -> aggh ; fused writes f32 d_out
    aggregate_kernel<<<gA, 256, 0, stream>>>(xh, adj, off, cnt, aggh, n);
    fused_kernel<true><<<gF, 256, LDS_BYTES, stream>>>(aggh, xh, Wl1, bl1, Wr1,
                                                       g1, be1, nullptr, y, n);
}